// Round 9
// baseline (270.064 us; speedup 1.0000x reference)
//
#include <hip/hip_runtime.h>

#define S_LEN  4096
#define DMODEL 1024
#define NHEAD  16
#define HDIM   64

typedef unsigned short u16;
typedef unsigned int   u32;
typedef __bf16 bf16x8 __attribute__((ext_vector_type(8)));
typedef float  f32x4  __attribute__((ext_vector_type(4)));

static __device__ __forceinline__ u16 f2b(float f) {
    union { __bf16 b; u16 u; } c; c.b = (__bf16)f; return c.u;
}

typedef __attribute__((address_space(3))) u32 lds_u32_t;
typedef __attribute__((address_space(1))) const u32 glb_u32_t;
static __device__ __forceinline__ void gload_lds16(const u16* g, u16* l) {
    __builtin_amdgcn_global_load_lds((glb_u32_t*)g, (lds_u32_t*)l, 16, 0, 0);
}

// ---------------------------------------------------------------------------
__global__ __launch_bounds__(256)
void convert_x(const float* __restrict__ x, u16* __restrict__ xb) {
    const int i0 = (blockIdx.x * 256 + threadIdx.x) * 8;
    float4 a = *reinterpret_cast<const float4*>(x + i0);
    float4 b = *reinterpret_cast<const float4*>(x + i0 + 4);
    u16 o[8] = {f2b(a.x), f2b(a.y), f2b(a.z), f2b(a.w),
                f2b(b.x), f2b(b.y), f2b(b.z), f2b(b.w)};
    *reinterpret_cast<uint4*>(xb + i0) = *reinterpret_cast<uint4*>(o);
}

__global__ __launch_bounds__(256)
void transpose_w4(const float* __restrict__ w0, const float* __restrict__ w1,
                  const float* __restrict__ w2, const float* __restrict__ w3,
                  u16* __restrict__ wT) {
    const int z = blockIdx.z;
    const float* w = (z == 0) ? w0 : (z == 1) ? w1 : (z == 2) ? w2 : w3;
    u16* dst0 = wT + (size_t)z * DMODEL * DMODEL;
    const int k0 = blockIdx.x * 64, n0 = blockIdx.y * 64;
    const int t = threadIdx.x;
    __shared__ u16 T[64][72];
    const int kk = t >> 4, nn = (t & 15) * 4;
    #pragma unroll
    for (int i = 0; i < 4; ++i) {
        float4 v = *reinterpret_cast<const float4*>(w + (size_t)(k0 + kk + i * 16) * DMODEL + n0 + nn);
        T[nn + 0][kk + i * 16] = f2b(v.x);
        T[nn + 1][kk + i * 16] = f2b(v.y);
        T[nn + 2][kk + i * 16] = f2b(v.z);
        T[nn + 3][kk + i * 16] = f2b(v.w);
    }
    __syncthreads();
    const int n = t >> 2, kc = (t & 3) * 16;
    uint4 r0 = *reinterpret_cast<const uint4*>(&T[n][kc]);
    uint4 r1 = *reinterpret_cast<const uint4*>(&T[n][kc + 8]);
    u16* dst = dst0 + (size_t)(n0 + n) * DMODEL + k0 + kc;
    *reinterpret_cast<uint4*>(dst)     = r0;
    *reinterpret_cast<uint4*>(dst + 8) = r1;
}

// ---------------------------------------------------------------------------
// 128x128-tile GEMM (m97 structure). MODE 0: fused QKV, out bf16 head-major;
// Q (tz==0) is pre-scaled by 0.125 so attention needs no score scaling.
// MODE 1: O-projection, out fp32.
template<int MODE>
__global__ __launch_bounds__(256, 2)
void gemm128(const u16* __restrict__ A, const u16* __restrict__ BT,
             const float* __restrict__ b0, const float* __restrict__ b1,
             const float* __restrict__ b2, void* __restrict__ Cout) {
    const int m0 = blockIdx.x * 128;
    const int ny = blockIdx.y;
    const int tz = (MODE == 0) ? (ny >> 3) : 0;
    const int n0 = (MODE == 0) ? ((ny & 7) * 128) : (ny * 128);
    const int tid = threadIdx.x, lane = tid & 63, w = tid >> 6;
    const int wr = w >> 1, wc = w & 1;
    const int fm = lane & 15, fq = lane >> 4;

    __shared__ u16 As[128][32];
    __shared__ u16 Bs[128][32];

    const u16* Bb = BT + (size_t)tz * DMODEL * DMODEL;

    f32x4 acc[4][4];
    #pragma unroll
    for (int i = 0; i < 4; ++i)
        #pragma unroll
        for (int t = 0; t < 4; ++t) acc[i][t] = f32x4{0.f, 0.f, 0.f, 0.f};

    const int srow = lane >> 2, scol = (lane & 3) * 8;

    for (int k0 = 0; k0 < DMODEL; k0 += 32) {
        #pragma unroll
        for (int r = 0; r < 2; ++r) {
            const int rowA = w * 32 + r * 16;
            gload_lds16(A  + (size_t)(m0 + rowA + srow) * DMODEL + k0 + scol, &As[rowA][0]);
            gload_lds16(Bb + (size_t)(n0 + rowA + srow) * DMODEL + k0 + scol, &Bs[rowA][0]);
        }
        __syncthreads();
        bf16x8 af[4], bf[4];
        #pragma unroll
        for (int i = 0; i < 4; ++i) af[i] = *reinterpret_cast<const bf16x8*>(&As[wr * 64 + i * 16 + fm][fq * 8]);
        #pragma unroll
        for (int t = 0; t < 4; ++t) bf[t] = *reinterpret_cast<const bf16x8*>(&Bs[wc * 64 + t * 16 + fm][fq * 8]);
        #pragma unroll
        for (int i = 0; i < 4; ++i)
            #pragma unroll
            for (int t = 0; t < 4; ++t)
                acc[i][t] = __builtin_amdgcn_mfma_f32_16x16x32_bf16(af[i], bf[t], acc[i][t], 0, 0, 0);
        __syncthreads();
    }

    const float* bp = (MODE == 0) ? ((tz == 0) ? b0 : (tz == 1) ? b1 : b2) : b0;
    const float scale = (MODE == 0 && tz == 0) ? 0.125f : 1.0f;
    #pragma unroll
    for (int t = 0; t < 4; ++t) {
        const int col = n0 + wc * 64 + t * 16 + fm;
        const float bias = bp[col];
        #pragma unroll
        for (int i = 0; i < 4; ++i) {
            #pragma unroll
            for (int r = 0; r < 4; ++r) {
                const int row = m0 + wr * 64 + i * 16 + fq * 4 + r;
                const float v = (acc[i][t][r] + bias) * scale;
                if (MODE == 0) {
                    const int hh = col >> 6, d = col & 63;
                    ((u16*)Cout)[(size_t)tz * S_LEN * DMODEL + ((size_t)hh * S_LEN + row) * HDIM + d] = f2b(v);
                } else {
                    ((float*)Cout)[(size_t)row * DMODEL + col] = v;
                }
            }
        }
    }
}

// ---------------------------------------------------------------------------
// Flash attention v4: K-split x2 (blockIdx.z = key half, 2048 keys each) for
// 1024 wgs = 4/CU. Single-buffered K/V (LDS 34.8 KB -> 4 wgs/CU), register
// prefetch, 2 barriers/iter hidden by 16 waves/CU. S^T = K*Q^T operand-swap
// (P^T packs as b64, zero conflicts). Q pre-scaled by 1/8 => exp(sacc) direct.
// Outputs: unnormalized fp32 numerator + denominator l per half.
__global__ __launch_bounds__(256, 4)
void attn_kernel(const u16* __restrict__ Q, const u16* __restrict__ K,
                 const u16* __restrict__ V, float* __restrict__ num,
                 float* __restrict__ lbuf) {
    const int qt = blockIdx.x, h = blockIdx.y, half = blockIdx.z;
    const int tid = threadIdx.x, lane = tid & 63, wid = tid >> 6;
    const int fm = lane & 15, fq = lane >> 4;

    __shared__ alignas(16) u16 Pt[128][68];   // [q][key], wave-private rows
    __shared__ alignas(16) u16 Ks[64][68];    // [key][d]  (single buffer)
    __shared__ alignas(16) u16 Vt[64][68];    // [d][key]

    const u16* Qh = Q + (size_t)h * S_LEN * HDIM;
    const u16* Kh = K + (size_t)h * S_LEN * HDIM;
    const u16* Vh = V + (size_t)h * S_LEN * HDIM;

    const int srow = tid >> 2, sch = (tid & 3) * 16;
    const int kp = tid & 31, vg = (tid >> 5) * 8;

    bf16x8 qf[2][2];
    #pragma unroll
    for (int rb = 0; rb < 2; ++rb) {
        const u16* qsrc = Qh + (size_t)(qt * 128 + wid * 32 + rb * 16 + fm) * HDIM + fq * 8;
        qf[rb][0] = *reinterpret_cast<const bf16x8*>(qsrc);
        qf[rb][1] = *reinterpret_cast<const bf16x8*>(qsrc + 32);
    }

    float rsum[2] = {0.f, 0.f};
    f32x4 oacc[2][4];
    #pragma unroll
    for (int rb = 0; rb < 2; ++rb)
        #pragma unroll
        for (int t = 0; t < 4; ++t) oacc[rb][t] = f32x4{0.f, 0.f, 0.f, 0.f};

    const int kt0 = half * (S_LEN / 128);          // 32 tiles per half
    const int kt1 = kt0 + (S_LEN / 128);

    uint4 kr0, kr1, vr0, vr1;
    {
        const u16* ks = Kh + (size_t)(kt0 * 64 + srow) * HDIM + sch;
        kr0 = *reinterpret_cast<const uint4*>(ks);
        kr1 = *reinterpret_cast<const uint4*>(ks + 8);
        const u16* vs = Vh + (size_t)(kt0 * 64 + 2 * kp) * HDIM + vg;
        vr0 = *reinterpret_cast<const uint4*>(vs);
        vr1 = *reinterpret_cast<const uint4*>(vs + HDIM);
    }

    for (int kt = kt0; kt < kt1; ++kt) {
        *reinterpret_cast<uint4*>(&Ks[srow][sch])     = kr0;
        *reinterpret_cast<uint4*>(&Ks[srow][sch + 8]) = kr1;
        {
            union { uint4 q; u16 hw[8]; } a, b;
            a.q = vr0; b.q = vr1;
            #pragma unroll
            for (int j = 0; j < 8; ++j) {
                u32 pk = (u32)a.hw[j] | ((u32)b.hw[j] << 16);
                *reinterpret_cast<u32*>(&Vt[vg + j][2 * kp]) = pk;
            }
        }
        __syncthreads();   // staging visible

        if (kt + 1 < kt1) {
            const u16* ks = Kh + (size_t)((kt + 1) * 64 + srow) * HDIM + sch;
            kr0 = *reinterpret_cast<const uint4*>(ks);
            kr1 = *reinterpret_cast<const uint4*>(ks + 8);
            const u16* vs = Vh + (size_t)((kt + 1) * 64 + 2 * kp) * HDIM + vg;
            vr0 = *reinterpret_cast<const uint4*>(vs);
            vr1 = *reinterpret_cast<const uint4*>(vs + HDIM);
        }

        // S^T = K * Q^T (Q pre-scaled by 1/8)
        f32x4 sacc[2][4];
        #pragma unroll
        for (int rb = 0; rb < 2; ++rb)
            #pragma unroll
            for (int mt = 0; mt < 4; ++mt) sacc[rb][mt] = f32x4{0.f, 0.f, 0.f, 0.f};
        #pragma unroll
        for (int kk2 = 0; kk2 < 2; ++kk2) {
            #pragma unroll
            for (int mt = 0; mt < 4; ++mt) {
                bf16x8 kf = *reinterpret_cast<const bf16x8*>(&Ks[mt * 16 + fm][kk2 * 32 + fq * 8]);
                #pragma unroll
                for (int rb = 0; rb < 2; ++rb)
                    sacc[rb][mt] = __builtin_amdgcn_mfma_f32_16x16x32_bf16(kf, qf[rb][kk2], sacc[rb][mt], 0, 0, 0);
            }
        }

        // P^T = exp(S^T), b64-packed writes
        #pragma unroll
        for (int rb = 0; rb < 2; ++rb) {
            #pragma unroll
            for (int mt = 0; mt < 4; ++mt) {
                float e0 = __expf(sacc[rb][mt][0]);
                float e1 = __expf(sacc[rb][mt][1]);
                float e2 = __expf(sacc[rb][mt][2]);
                float e3 = __expf(sacc[rb][mt][3]);
                rsum[rb] += (e0 + e1) + (e2 + e3);
                u32 p0 = (u32)f2b(e0) | ((u32)f2b(e1) << 16);
                u32 p1 = (u32)f2b(e2) | ((u32)f2b(e3) << 16);
                *reinterpret_cast<uint2*>(&Pt[wid * 32 + rb * 16 + fm][mt * 16 + fq * 4]) =
                    uint2{p0, p1};
            }
        }

        // O += P V
        #pragma unroll
        for (int kk2 = 0; kk2 < 2; ++kk2) {
            bf16x8 af[2];
            #pragma unroll
            for (int rb = 0; rb < 2; ++rb)
                af[rb] = *reinterpret_cast<const bf16x8*>(&Pt[wid * 32 + rb * 16 + fm][kk2 * 32 + fq * 8]);
            #pragma unroll
            for (int t = 0; t < 4; ++t) {
                bf16x8 bf = *reinterpret_cast<const bf16x8*>(&Vt[t * 16 + fm][kk2 * 32 + fq * 8]);
                #pragma unroll
                for (int rb = 0; rb < 2; ++rb)
                    oacc[rb][t] = __builtin_amdgcn_mfma_f32_16x16x32_bf16(af[rb], bf, oacc[rb][t], 0, 0, 0);
            }
        }
        __syncthreads();   // all reads done before next overwrite
    }

    // write unnormalized numerator (fp32) + denominator
    float* numh = num + (size_t)half * S_LEN * DMODEL;
    #pragma unroll
    for (int rb = 0; rb < 2; ++rb) {
        #pragma unroll
        for (int t = 0; t < 4; ++t) {
            const int d = t * 16 + fm;
            #pragma unroll
            for (int r = 0; r < 4; ++r) {
                const int row = qt * 128 + wid * 32 + rb * 16 + fq * 4 + r;
                numh[(size_t)row * DMODEL + h * HDIM + d] = oacc[rb][t][r];
            }
        }
        float rs = rsum[rb];
        rs += __shfl_xor(rs, 16, 64);
        rs += __shfl_xor(rs, 32, 64);
        if (fq == 0) {
            const int qrow = qt * 128 + wid * 32 + rb * 16 + fm;
            lbuf[((size_t)half * NHEAD + h) * S_LEN + qrow] = rs;
        }
    }
}

// out_bf16[row][col] = (num0+num1)/(l0+l1), col's head = col>>6
__global__ __launch_bounds__(256)
void reduce_halves(const float* __restrict__ num, const float* __restrict__ lbuf,
                   u16* __restrict__ Ob) {
    const int i0 = (blockIdx.x * 256 + threadIdx.x) * 8;
    const int row = i0 >> 10, col = i0 & 1023;
    const int h = col >> 6;
    const float l = lbuf[(size_t)h * S_LEN + row] +
                    lbuf[((size_t)NHEAD + h) * S_LEN + row];
    const float inv = 1.0f / l;
    const float* n0 = num + i0;
    const float* n1 = num + (size_t)S_LEN * DMODEL + i0;
    float4 a0 = *reinterpret_cast<const float4*>(n0);
    float4 a1 = *reinterpret_cast<const float4*>(n0 + 4);
    float4 b0 = *reinterpret_cast<const float4*>(n1);
    float4 b1 = *reinterpret_cast<const float4*>(n1 + 4);
    u16 o[8] = {f2b((a0.x + b0.x) * inv), f2b((a0.y + b0.y) * inv),
                f2b((a0.z + b0.z) * inv), f2b((a0.w + b0.w) * inv),
                f2b((a1.x + b1.x) * inv), f2b((a1.y + b1.y) * inv),
                f2b((a1.z + b1.z) * inv), f2b((a1.w + b1.w) * inv)};
    *reinterpret_cast<uint4*>(Ob + i0) = *reinterpret_cast<uint4*>(o);
}

extern "C" void kernel_launch(void* const* d_in, const int* in_sizes, int n_in,
                              void* d_out, int out_size, void* d_ws, size_t ws_size,
                              hipStream_t stream) {
    const float* x  = (const float*)d_in[0];
    const float* wq = (const float*)d_in[1];
    const float* bq = (const float*)d_in[2];
    const float* wk = (const float*)d_in[3];
    const float* bk = (const float*)d_in[4];
    const float* wv = (const float*)d_in[5];
    const float* bv = (const float*)d_in[6];
    const float* wo = (const float*)d_in[7];
    const float* bo = (const float*)d_in[8];

    u16* ws = (u16*)d_ws;
    const size_t MW  = (size_t)DMODEL * DMODEL;
    const size_t NX  = (size_t)S_LEN * DMODEL;
    const size_t TSZ = (size_t)NHEAD * S_LEN * HDIM;

    u16* xb = ws;                       // 4Mi u16
    u16* WT = xb + NX;                  // 4Mi
    u16* Qb = WT + 4 * MW;              // 12Mi (Q,K,V)
    u16* Ob = Qb + 3 * TSZ;             // 4Mi
    float* num  = (float*)(Ob + NX);    // 8Mi fp32 (2 halves)
    float* lbuf = num + 2 * NX;         // 128Ki fp32
                                        // total ~80.5 MB ws

    hipLaunchKernelGGL(convert_x, dim3(NX / 2048), dim3(256), 0, stream, x, xb);
    hipLaunchKernelGGL(transpose_w4, dim3(16, 16, 4), dim3(256), 0, stream, wq, wk, wv, wo, WT);

    hipLaunchKernelGGL((gemm128<0>), dim3(S_LEN / 128, 24), dim3(256), 0, stream,
                       xb, WT, bq, bk, bv, (void*)Qb);
    hipLaunchKernelGGL(attn_kernel, dim3(S_LEN / 128, NHEAD, 2), dim3(256), 0, stream,
                       Qb, Qb + TSZ, Qb + 2 * TSZ, num, lbuf);
    hipLaunchKernelGGL(reduce_halves, dim3(NX / 2048), dim3(256), 0, stream, num, lbuf, Ob);
    hipLaunchKernelGGL((gemm128<1>), dim3(S_LEN / 128, 8), dim3(256), 0, stream,
                       Ob, WT + 3 * MW, bo, bo, bo, d_out);
}